// Round 5
// baseline (684.937 us; speedup 1.0000x reference)
//
#include <hip/hip_runtime.h>

// ReLU-RNN B=8192, T=1024, I=7, H=100, O=1 — barrier-free MFMA recurrence.
//
// v6: SPLIT ACC CHAINS + DE-SHARED MFMA STREAM. Model fit over v1-v5:
// T_step = max(chain term, issue term). v1's floor 1007cy is either
// (i) 4 dependent MFMA links x ~250cy, or (ii) ~36cy/MFMA cadence when
// adjacent MFMAs share the same B-operand register quad (v2 measured
// ~28cy de-shared). v6 splits each acc[ti] into TWO independent 2-deep
// chains: accE = kt0->kt1, accO = kt2->kt3, merged with v_pk_add_f32
// inside the repack (14 extra VALU — v5 proved VALU count doesn't bind).
// Issue order interleaves kt0 with kt2 (then kt1 with kt3), so adjacent
// MFMAs alternate hf0/hf2 (hf1/hf3): no shared B adjacency, no shared acc.
// Both models predict T ~ 650-850cy (was 1007-1042).
//
// Grid 512x64: 1 wave/SIMD (v2/v4 proved total = 1024 x per-wave step
// latency; idle SIMDs are irrelevant, per-wave work is everything).
//
// Permuted-index scheme unchanged:
//   D position (ti, q, r) [n' = 16ti+4q+r, batch m = lane&15] maps to
//   B slot k' = 32kt + 8q + jj ; kt=3,jj>=4 slots carry x0..x6 and bias.

typedef _Float16 half8 __attribute__((ext_vector_type(8)));
typedef float f32x4 __attribute__((ext_vector_type(4)));
typedef unsigned u32x4 __attribute__((ext_vector_type(4)));

static __device__ __forceinline__ unsigned pkrtz(float a, float b) {
    return __builtin_bit_cast(unsigned, __builtin_amdgcn_cvt_pkrtz(a, b));
}

// 4-byte-aligned float4 load (x rows have stride 7 floats; t*7 is odd-dword)
static __device__ __forceinline__ f32x4 ld4(const float* p) {
    typedef f32x4 __attribute__((aligned(4))) f32x4a;
    return *(const f32x4a*)p;
}

// sum the E/O partial chains and relu-pack two acc pairs into one B half8
static __device__ __forceinline__ half8 pack_relu(f32x4 e0, f32x4 o0,
                                                  f32x4 e1, f32x4 o1) {
    const u32x4 zz = {0u, 0u, 0u, 0u};
    const half8 hz = __builtin_bit_cast(half8, zz);
    f32x4 s0 = e0 + o0;              // 2x v_pk_add_f32
    f32x4 s1 = e1 + o1;
    u32x4 d;
    d.x = pkrtz(s0[0], s0[1]);
    d.y = pkrtz(s0[2], s0[3]);
    d.z = pkrtz(s1[0], s1[1]);
    d.w = pkrtz(s1[2], s1[3]);
    return __builtin_elementwise_max(__builtin_bit_cast(half8, d), hz);
}

// sched_group_barrier masks: VALU=0x2, MFMA=0x8, VMEM_READ=0x20
#define SGB(mask, n) __builtin_amdgcn_sched_group_barrier(mask, n, 0)
#define MFMA16(a, b, c) __builtin_amdgcn_mfma_f32_16x16x32_f16(a, b, c, 0, 0, 0)

__global__ __launch_bounds__(64, 1)
void rnn_wave(const float* __restrict__ x,
              const float* __restrict__ W_ih,
              const float* __restrict__ W_hh,
              const float* __restrict__ b_ih,
              const float* __restrict__ b_hh,
              const float* __restrict__ W_fc,
              const float* __restrict__ b_fc,
              float* __restrict__ out) {
    const int l  = threadIdx.x;
    const int lm = l & 15;           // batch row within tile
    const int q  = l >> 4;           // quad
    const bool q1 = (q == 1);

    // ---- W' fragments (constant for all 1024 steps; 7 tiles x 4 kt) ----
    half8 w[7][4];
#pragma unroll
    for (int ti = 0; ti < 7; ++ti) {
        const int np = 16 * ti + lm;                  // output row n'
#pragma unroll
        for (int kt = 0; kt < 4; ++kt) {
            half8 hw;
#pragma unroll
            for (int jj = 0; jj < 8; ++jj) {
                float v = 0.f;
                if (np < 100) {
                    if (jj < 4) {                     // h slot, p = 16kt+4q+jj
                        int p = 16 * kt + 4 * q + jj;
                        if (p < 100) v = W_hh[np * 100 + p];
                    } else if (kt < 3) {              // h slot, p = 16(kt+4)+4q+(jj-4)
                        int p = 16 * (kt + 4) + 4 * q + (jj - 4);
                        if (p < 100) v = W_hh[np * 100 + p];
                    } else {                          // kt==3, jj>=4: x / bias slots
                        if (q == 0)      v = W_ih[np * 7 + (jj - 4)];      // x0..x3
                        else if (q == 1) v = (jj < 7) ? W_ih[np * 7 + jj]  // x4..x6
                                             : (b_ih[np] + b_hh[np]);     // bias @ jj=7
                        // q>=2: stays 0 — their hf[3] tail is don't-care
                    }
                }
                hw[jj] = (_Float16)v;
            }
            w[ti][kt] = hw;
        }
    }

    // ---- x addressing: one raw dwordx4 per step per lane ----
    const float* xr = x + (size_t)(blockIdx.x * 16 + lm) * 7168;
    const int xo = q1 ? 3 : 0;       // q1 reads (x3,x4,x5,x6); others (x0..x3)

    // depth-4 x prefetch ring: slot t&3 holds RAW dwordx4 of x_t.
    // Component select deferred to consumption (4 steps after the load).
    f32x4 xv[4];
#pragma unroll
    for (int s = 0; s < 4; ++s) xv[s] = ld4(xr + s * 7 + xo);

    const f32x4 kZ = {0.f, 0.f, 0.f, 0.f};
    f32x4 accE[7], accO[7];
#pragma unroll
    for (int i = 0; i < 7; ++i) { accE[i] = kZ; accO[i] = kZ; }
    half8 hf[4];

    for (int tb = 0; tb < 1024; tb += 4) {
#pragma unroll
        for (int u = 0; u < 4; ++u) {
            const int t = tb + u;

            // ---- hf0, hf2 <- relu-pack(prev E+O sums) — phase-1 inputs ----
            hf[0] = pack_relu(accE[0], accO[0], accE[4], accO[4]);
            hf[2] = pack_relu(accE[2], accO[2], accE[6], accO[6]);
            SGB(0x2, 24);

            // ---- phase 1: kt0 (C=0 -> accE) interleaved with kt2 (C=0 -> accO)
            // adjacent MFMAs alternate hf0/hf2: no B-operand sharing.
            accE[0] = MFMA16(w[0][0], hf[0], kZ);
            accO[0] = MFMA16(w[0][2], hf[2], kZ);
            accE[4] = MFMA16(w[4][0], hf[0], kZ);
            accO[4] = MFMA16(w[4][2], hf[2], kZ);
            SGB(0x8, 4);
            // hf1 pack reads PREV accE/O[1],[5] (SSA: before their overwrite)
            hf[1] = pack_relu(accE[1], accO[1], accE[5], accO[5]);
            SGB(0x2, 12);
            accE[1] = MFMA16(w[1][0], hf[0], kZ);
            accO[1] = MFMA16(w[1][2], hf[2], kZ);
            accE[5] = MFMA16(w[5][0], hf[0], kZ);
            accO[5] = MFMA16(w[5][2], hf[2], kZ);
            SGB(0x8, 4);
            {
                // hf3: relu'd h part (prev accE/O[3] sum) + raw x_t/bias words.
                // q-select at consumption, 4 steps after the load retired.
                f32x4 s3 = accE[3] + accO[3];
                f32x4 v = xv[u];
                float a_ = q1 ? v.y : v.x, b_ = q1 ? v.z : v.y;
                float c_ = q1 ? v.w : v.z, e_ = q1 ? 1.0f : v.w;
                u32x4 d;
                d.x = pkrtz(fmaxf(s3[0], 0.f), fmaxf(s3[1], 0.f));
                d.y = pkrtz(fmaxf(s3[2], 0.f), fmaxf(s3[3], 0.f));
                d.z = pkrtz(a_, b_);
                d.w = pkrtz(c_, e_);
                hf[3] = __builtin_bit_cast(half8, d);
            }
            SGB(0x2, 14);
            accE[2] = MFMA16(w[2][0], hf[0], kZ);
            accO[2] = MFMA16(w[2][2], hf[2], kZ);
            accE[6] = MFMA16(w[6][0], hf[0], kZ);
            accO[6] = MFMA16(w[6][2], hf[2], kZ);
            accE[3] = MFMA16(w[3][0], hf[0], kZ);
            accO[3] = MFMA16(w[3][2], hf[2], kZ);
            SGB(0x8, 6);

            // refill slot u with x_{t+4} raw (consumed 4 steps from now)
            {
                int tn = t + 4; if (tn > 1023) tn = 1023;
                xv[u] = ld4(xr + tn * 7 + xo);
            }
            SGB(0x20, 1);

            // ---- phase 2: kt1 (C=accE) interleaved with kt3 (C=accO) ----
            // {0,4,...} order so accE/O[0] retire first for next-iter hf0.
            accE[0] = MFMA16(w[0][1], hf[1], accE[0]);
            accO[0] = MFMA16(w[0][3], hf[3], accO[0]);
            accE[4] = MFMA16(w[4][1], hf[1], accE[4]);
            accO[4] = MFMA16(w[4][3], hf[3], accO[4]);
            accE[1] = MFMA16(w[1][1], hf[1], accE[1]);
            accO[1] = MFMA16(w[1][3], hf[3], accO[1]);
            accE[5] = MFMA16(w[5][1], hf[1], accE[5]);
            accO[5] = MFMA16(w[5][3], hf[3], accO[5]);
            accE[2] = MFMA16(w[2][1], hf[1], accE[2]);
            accO[2] = MFMA16(w[2][3], hf[3], accO[2]);
            accE[6] = MFMA16(w[6][1], hf[1], accE[6]);
            accO[6] = MFMA16(w[6][3], hf[3], accO[6]);
            accE[3] = MFMA16(w[3][1], hf[1], accE[3]);
            accO[3] = MFMA16(w[3][3], hf[3], accO[3]);
            SGB(0x8, 14);
        }
    }

    // ---- epilogue: accE+accO = pre-relu h_T (permuted space, batch = lm) ----
    float sum = 0.f;
#pragma unroll
    for (int ti = 0; ti < 7; ++ti) {
#pragma unroll
        for (int r = 0; r < 4; ++r) {
            const int np = 16 * ti + 4 * q + r;
            const float wf = (np < 100) ? W_fc[np] : 0.f;
            sum += wf * fmaxf(accE[ti][r] + accO[ti][r], 0.f);
        }
    }
    sum += __shfl_xor(sum, 16, 64);   // reduce across the 4 q-lanes of row lm
    sum += __shfl_xor(sum, 32, 64);
    if (q == 0) out[blockIdx.x * 16 + lm] = sum + b_fc[0];
}

extern "C" void kernel_launch(void* const* d_in, const int* in_sizes, int n_in,
                              void* d_out, int out_size, void* d_ws, size_t ws_size,
                              hipStream_t stream) {
    const float* x    = (const float*)d_in[0];
    const float* W_ih = (const float*)d_in[1];
    const float* W_hh = (const float*)d_in[2];
    const float* b_ih = (const float*)d_in[3];
    const float* b_hh = (const float*)d_in[4];
    const float* W_fc = (const float*)d_in[5];
    const float* b_fc = (const float*)d_in[6];
    float* out = (float*)d_out;

    rnn_wave<<<dim3(512), dim3(64), 0, stream>>>(x, W_ih, W_hh, b_ih, b_hh, W_fc, b_fc, out);
}

// Round 6
// 665.433 us; speedup vs baseline: 1.0293x; 1.0293x over previous
//
#include <hip/hip_runtime.h>

// ReLU-RNN B=8192, T=1024, I=7, H=100, O=1 — 2-wave H-split MFMA recurrence.
//
// v7: model from v1-v6: a lone wave's step = MFMA issue-occupancy + VALU,
// fully serialized (forced interleave null in v5/v6; co-resident waves just
// share the pipe, v2/v4). Only lever left: fewer MFMAs per wave. Each batch
// tile's H-space is split across 2 waves on different SIMDs of one CU:
//   wave0: ti 0..3 (16 MFMA/step) -> produces hf[kt].x/.y dwords, kt=0..3
//   wave1: ti 4..6 (12 MFMA/step) -> produces hf[kt].z/.w dwords, kt=0..2
//   hf[3].z/.w = x/bias words, computed lane-locally by both waves.
// Exchange via LDS (8B/lane/kt), double-buffered by step parity, ONE raw
// s_barrier per step. Raw barrier + manual lgkmcnt (NOT __syncthreads) so
// the depth-4 x-prefetch vmcnt is never drained at the barrier.
// 512 blocks x 128 thr = 1024 waves = 1/SIMD chip-wide (was 512 SIMDs).
//
// Permuted-index scheme unchanged from v1 (verified):
//   D position (ti, q, r) [n' = 16ti+4q+r, batch m = lane&15] maps to
//   B slot k' = 32kt + 8q + jj ; kt=3,jj>=4 slots carry x0..x6 and bias.
//   v1's hf[kt] = {pack(acc[kt]), pack(acc[kt+4])} -> wave0 owns the low
//   dwords (acc[0..3]), wave1 the high dwords (acc[4..6]). Same arithmetic,
//   just distributed.

typedef _Float16 half8 __attribute__((ext_vector_type(8)));
typedef _Float16 half4 __attribute__((ext_vector_type(4)));
typedef float f32x4 __attribute__((ext_vector_type(4)));
typedef unsigned u32x4 __attribute__((ext_vector_type(4)));
typedef unsigned u32x2 __attribute__((ext_vector_type(2)));

static __device__ __forceinline__ unsigned pkrtz(float a, float b) {
    return __builtin_bit_cast(unsigned, __builtin_amdgcn_cvt_pkrtz(a, b));
}
// 4-byte-aligned float4 load (x rows have stride 7 floats)
static __device__ __forceinline__ f32x4 ld4(const float* p) {
    typedef f32x4 __attribute__((aligned(4))) f32x4a;
    return *(const f32x4a*)p;
}
// pack one f32x4 acc to 2 dwords of f16 pairs, relu'd (RTZ-exact: relu
// after pack == pack after relu, verified since v2)
static __device__ __forceinline__ u32x2 relu_pack(const f32x4 a) {
    u32x2 u = { pkrtz(a[0], a[1]), pkrtz(a[2], a[3]) };
    half4 h = __builtin_bit_cast(half4, u);
    const half4 z = { (_Float16)0, (_Float16)0, (_Float16)0, (_Float16)0 };
    h = __builtin_elementwise_max(h, z);
    return __builtin_bit_cast(u32x2, h);
}

#define MFMA16(a, b, c) __builtin_amdgcn_mfma_f32_16x16x32_f16(a, b, c, 0, 0, 0)

template<int NT, int TI0, int WID>
static __device__ __forceinline__ void rnn_half(
    const int l, const int lm, const int q, const bool q1,
    const float* __restrict__ x,
    const float* __restrict__ W_ih, const float* __restrict__ W_hh,
    const float* __restrict__ b_ih, const float* __restrict__ b_hh,
    const float* __restrict__ W_fc, const float* __restrict__ b_fc,
    float* __restrict__ out,
    u32x2 (*xch)[2][4][64], float* red)
{
    // ---- W' fragments for this wave's ti range ----
    half8 w[NT][4];
#pragma unroll
    for (int i = 0; i < NT; ++i) {
        const int np = 16 * (TI0 + i) + lm;          // output row n'
#pragma unroll
        for (int kt = 0; kt < 4; ++kt) {
            half8 hw;
#pragma unroll
            for (int jj = 0; jj < 8; ++jj) {
                float v = 0.f;
                if (np < 100) {
                    if (jj < 4) {                     // h slot, p = 16kt+4q+jj
                        int p = 16 * kt + 4 * q + jj;
                        if (p < 100) v = W_hh[np * 100 + p];
                    } else if (kt < 3) {              // h slot, p = 16(kt+4)+4q+(jj-4)
                        int p = 16 * (kt + 4) + 4 * q + (jj - 4);
                        if (p < 100) v = W_hh[np * 100 + p];
                    } else {                          // kt==3, jj>=4: x / bias slots
                        if (q == 0)      v = W_ih[np * 7 + (jj - 4)];      // x0..x3
                        else if (q == 1) v = (jj < 7) ? W_ih[np * 7 + jj]  // x4..x6
                                             : (b_ih[np] + b_hh[np]);     // bias @ jj=7
                    }
                }
                hw[jj] = (_Float16)v;
            }
            w[i][kt] = hw;
        }
    }

    // ---- x addressing (both waves load the same rows; L1 absorbs) ----
    const float* xr = x + (size_t)(blockIdx.x * 16 + lm) * 7168;
    const int xo = q1 ? 3 : 0;       // q1 reads (x3..x6) -> .yzw + 1.0

    const u32x4 zz = {0u, 0u, 0u, 0u};
    const half8 hz = __builtin_bit_cast(half8, zz);

    // hf for t=0: h=0, x_0/bias in kt=3 tail
    half8 hf[4];
    {
        f32x4 v = ld4(xr + xo);
        float x0 = q1 ? v.y : v.x, x1 = q1 ? v.z : v.y;
        float x2 = q1 ? v.w : v.z, x3 = q1 ? 1.0f : v.w;
        hf[0] = hz; hf[1] = hz; hf[2] = hz;
        u32x4 h3 = {0u, 0u, pkrtz(x0, x1), pkrtz(x2, x3)};
        hf[3] = __builtin_bit_cast(half8, h3);
    }

    // depth-4 raw x prefetch ring; select deferred to consumption
    f32x4 xv[4];
#pragma unroll
    for (int s = 1; s <= 4; ++s) xv[s & 3] = ld4(xr + s * 7 + xo);

    const f32x4 kZ = {0.f, 0.f, 0.f, 0.f};
    f32x4 acc[NT];
#pragma unroll
    for (int i = 0; i < NT; ++i) acc[i] = kZ;

    for (int tb = 0; tb < 1024; tb += 4) {
#pragma unroll
        for (int u = 0; u < 4; ++u) {
            const int t = tb + u;
            const int p = u & 1;                     // LDS parity (t&1)

            // ---- MFMA block: own ti range, all kt ----
#pragma unroll
            for (int kt = 0; kt < 4; ++kt)
#pragma unroll
                for (int i = 0; i < NT; ++i)
                    acc[i] = MFMA16(w[i][kt], hf[kt], kt == 0 ? kZ : acc[i]);

            // ---- pack own dwords (relu'd) and write to LDS ----
            u32x2 own[NT];
#pragma unroll
            for (int i = 0; i < NT; ++i) {
                own[i] = relu_pack(acc[i]);
                xch[p][WID][i][l] = own[i];
            }

            asm volatile("s_waitcnt lgkmcnt(0)" ::: "memory");  // writes visible
            __builtin_amdgcn_s_barrier();
            asm volatile("" ::: "memory");

            // ---- read partner's dwords ----
            constexpr int NR = 7 - NT;
            u32x2 rd[NR];
#pragma unroll
            for (int j = 0; j < NR; ++j) rd[j] = xch[p][WID ^ 1][j][l];

            // x words for hf[3] tail (consume slot s, then refill with t+5)
            const int s = (u + 1) & 3;
            unsigned xd0, xd1;
            {
                f32x4 v = xv[s];
                float a_ = q1 ? v.y : v.x, b_ = q1 ? v.z : v.y;
                float c_ = q1 ? v.w : v.z, e_ = q1 ? 1.0f : v.w;
                xd0 = pkrtz(a_, b_); xd1 = pkrtz(c_, e_);
            }
            {
                int tn = t + 5; if (tn > 1023) tn = 1023;
                xv[s] = ld4(xr + tn * 7 + xo);
            }

            // ---- assemble hf for step t+1 ----
#pragma unroll
            for (int kt = 0; kt < 3; ++kt) {
                u32x2 lo, hi;
                if constexpr (WID == 0) { lo = own[kt]; hi = rd[kt]; }
                else                    { lo = rd[kt];  hi = own[kt]; }
                u32x4 d = { lo.x, lo.y, hi.x, hi.y };
                hf[kt] = __builtin_bit_cast(half8, d);
            }
            {
                u32x2 lo;
                if constexpr (WID == 0) lo = own[3]; else lo = rd[3];
                u32x4 d = { lo.x, lo.y, xd0, xd1 };
                hf[3] = __builtin_bit_cast(half8, d);
            }
        }
    }

    // ---- epilogue: acc = pre-relu h_T rows for own ti range ----
    float sum = 0.f;
#pragma unroll
    for (int i = 0; i < NT; ++i)
#pragma unroll
        for (int r = 0; r < 4; ++r) {
            const int np = 16 * (TI0 + i) + 4 * q + r;
            const float wf = (np < 100) ? W_fc[np] : 0.f;
            sum += wf * fmaxf(acc[i][r], 0.f);
        }
    if constexpr (WID == 1) red[l] = sum;
    asm volatile("s_waitcnt lgkmcnt(0)" ::: "memory");
    __builtin_amdgcn_s_barrier();
    asm volatile("" ::: "memory");
    if constexpr (WID == 0) {
        float s2 = sum + red[l];
        s2 += __shfl_xor(s2, 16, 64);   // reduce across the 4 q-lanes of row lm
        s2 += __shfl_xor(s2, 32, 64);
        if (q == 0) out[blockIdx.x * 16 + lm] = s2 + b_fc[0];
    }
}

__global__ __launch_bounds__(128, 1)
void rnn_wave(const float* __restrict__ x,
              const float* __restrict__ W_ih,
              const float* __restrict__ W_hh,
              const float* __restrict__ b_ih,
              const float* __restrict__ b_hh,
              const float* __restrict__ W_fc,
              const float* __restrict__ b_fc,
              float* __restrict__ out) {
    __shared__ u32x2 xch[2][2][4][64];   // [parity][writer][kt][lane] 8 KB
    __shared__ float red[64];

    const int l  = threadIdx.x & 63;
    const int wv = threadIdx.x >> 6;     // wave 0/1 -> different SIMDs
    const int lm = l & 15;
    const int q  = l >> 4;
    const bool q1 = (q == 1);

    if (wv == 0)
        rnn_half<4, 0, 0>(l, lm, q, q1, x, W_ih, W_hh, b_ih, b_hh, W_fc, b_fc,
                          out, xch, red);
    else
        rnn_half<3, 4, 1>(l, lm, q, q1, x, W_ih, W_hh, b_ih, b_hh, W_fc, b_fc,
                          out, xch, red);
}

extern "C" void kernel_launch(void* const* d_in, const int* in_sizes, int n_in,
                              void* d_out, int out_size, void* d_ws, size_t ws_size,
                              hipStream_t stream) {
    const float* x    = (const float*)d_in[0];
    const float* W_ih = (const float*)d_in[1];
    const float* W_hh = (const float*)d_in[2];
    const float* b_ih = (const float*)d_in[3];
    const float* b_hh = (const float*)d_in[4];
    const float* W_fc = (const float*)d_in[5];
    const float* b_fc = (const float*)d_in[6];
    float* out = (float*)d_out;

    rnn_wave<<<dim3(512), dim3(128), 0, stream>>>(x, W_ih, W_hh, b_ih, b_hh, W_fc, b_fc, out);
}